// Round 7
// baseline (5190.545 us; speedup 1.0000x reference)
//
#include <hip/hip_runtime.h>
#include <stdint.h>

// Farthest point sampling, pointops semantics.
// B=8 batches, n=65536, stride=64 -> m=1024 samples/batch.
// 16 WGs/batch, coords in LDS (transposed, conflict-free, volatile reads ->
// no register-promotion/spill games: round-6 bug). Per-step sync: each WAVE
// publishes one self-contained packed key (it|dist|~idx) to its own slot
// (64 slots/batch, one per lane); every wave polls all 64 slots with relaxed
// agent (sc1) loads and reduces keys with shfl_xor. No atomicMax, no arrival
// counter, no acquire (no buffer_inv), and NO __syncthreads in the loop.
//
// Safety: slot tags are monotone (+2 per parity cell). Overwrite of slot s's
// parity cell for step it happens at publish(it+2) by wave s, which requires
// wave s to have passed poll(it+1), which requires every wave to have
// published it+1, which each wave does only AFTER its poll(it) loads
// resolved (wave program order). So no reader of step it's cell can see the
// it+2 value, and overshoot-deadlock is impossible by the same induction.
// comm region is memset every launch -> replay-deterministic.

#define G     16     // workgroups per batch
#define BS    256    // threads per workgroup (4 waves)
#define PPT   16     // points per thread (G*BS*PPT == n)
#define NSLOT 64     // slots per batch = G * 4 waves = one per lane

typedef unsigned long long u64;
typedef unsigned int u32;

// key layout: [63:48]=it  [47:16]=float bits of best dist (nonneg)
//             [15:0]=0xFFFF-idx
// nonneg IEEE floats compare like their bit patterns; larger (0xFFFF-idx)
// wins => smaller idx wins ties (numpy argmax first-max semantics).

__global__ __launch_bounds__(BS, 1)
void fps_slots(const float* __restrict__ p, int n, int m,
               u64* __restrict__ comm,
               float* __restrict__ out_np, float* __restrict__ out_no,
               float* __restrict__ out_idx)
{
#pragma clang fp contract(off)
    const int bg   = blockIdx.x;
    const int b    = bg / G;
    const int g    = bg % G;
    const int t    = threadIdx.x;
    const int lane = t & 63;
    const int w    = t >> 6;
    const int gbase  = b * n;            // global point base of this batch
    const int wgbase = g * (BS * PPT);   // batch-local base of this WG
    const int sidx   = g * 4 + w;        // this wave's slot (0..63)

    __shared__ float xs[BS * PPT], ys[BS * PPT], zs[BS * PPT];  // 48 KB

    // ---- stage coords into LDS, transposed: [j*BS + t] = pt wgbase+t*PPT+j
    {
        const float* pb = p + 3ull * (u32)(gbase + wgbase + t * PPT);
#pragma unroll
        for (int j = 0; j < PPT; ++j) {
            xs[j * BS + t] = pb[3 * j + 0];
            ys[j * BS + t] = pb[3 * j + 1];
            zs[j * BS + t] = pb[3 * j + 2];
        }
    }
    __syncthreads();   // LDS ready; the only barrier in the kernel

    // volatile: force ds_read each step (deterministic cost, no promotion)
    const volatile float* vxs = xs;
    const volatile float* vys = ys;
    const volatile float* vzs = zs;

    float dist[PPT];
#pragma unroll
    for (int j = 0; j < PPT; ++j) dist[j] = 1e10f;

    // first query = point 0 of the batch
    float qx = p[3ull * (u32)gbase + 0];
    float qy = p[3ull * (u32)gbase + 1];
    float qz = p[3ull * (u32)gbase + 2];

    if (g == 0 && t == 0) {
        out_idx[(size_t)b * m] = (float)gbase;
        out_np[(size_t)(b * m) * 3 + 0] = qx;
        out_np[(size_t)(b * m) * 3 + 1] = qy;
        out_np[(size_t)(b * m) * 3 + 2] = qz;
        out_no[b] = (float)((b + 1) * m);
    }

    // per-batch comm: 2 parities x 64 slots x u64 = 1024 B
    u64* sb0 = comm + (size_t)b * (2 * NSLOT);

    for (int it = 1; it < m; ++it) {
        // ---- local distance update + per-thread argmax (ids ascend in j) ----
        float best = -1.0f;
        int   bj   = 0;
#pragma unroll
        for (int j = 0; j < PPT; ++j) {
            float x = vxs[j * BS + t];
            float y = vys[j * BS + t];
            float z = vzs[j * BS + t];
            float dx = x - qx;
            float dy = y - qy;
            float dz = z - qz;
            float d  = dx * dx + dy * dy + dz * dz;   // contract off: left-assoc
            float nd = fminf(dist[j], d);
            dist[j] = nd;
            if (nd > best) { best = nd; bj = j; }     // strict > keeps earliest
        }
        int bidx = wgbase + t * PPT + bj;             // batch-local winner idx

        // ---- wave argmax (64 lanes; ids ascend with lane, explicit tie-break)
#pragma unroll
        for (int off = 1; off < 64; off <<= 1) {
            float ov = __shfl_xor(best, off);
            int   oi = __shfl_xor(bidx, off);
            if (ov > best || (ov == best && oi < bidx)) { best = ov; bidx = oi; }
        }

        u64* sb = sb0 + (size_t)(it & 1) * NSLOT;

        // ---- lane 0: publish this wave's self-contained candidate key ----
        if (lane == 0) {
            u64 k = ((u64)(u32)it << 48)
                  | ((u64)(u32)__float_as_uint(best) << 16)
                  | (u64)(u32)(0xFFFF - bidx);
            __hip_atomic_store(sb + sidx, k, __ATOMIC_RELAXED,
                               __HIP_MEMORY_SCOPE_AGENT);
        }

        // ---- all lanes: poll slot[lane] until tagged it (relaxed sc1) ----
        u64 k;
        bool ok;
        do {
            k = __hip_atomic_load(sb + lane, __ATOMIC_RELAXED,
                                  __HIP_MEMORY_SCOPE_AGENT);
            ok = ((u32)(k >> 48) == (u32)it);
        } while (!__all(ok));

        // ---- wave max over 64 keys: (it,dist,-idx) lexicographic ----
#pragma unroll
        for (int off = 1; off < 64; off <<= 1) {
            u64 k2 = __shfl_xor(k, off);
            if (k2 > k) k = k2;
        }
        int kidx = 0xFFFF - (int)(k & 0xFFFF);

        // winner coords from read-only p (L3-warm; loop has no cache-inv ops)
        const float* wp = p + 3ull * (u32)(gbase + kidx);
        qx = wp[0]; qy = wp[1]; qz = wp[2];

        if (g == 0 && t == 0) {
            out_idx[(size_t)b * m + it] = (float)(gbase + kidx);
            out_np[(size_t)(b * m + it) * 3 + 0] = qx;
            out_np[(size_t)(b * m + it) * 3 + 1] = qy;
            out_np[(size_t)(b * m + it) * 3 + 2] = qz;
        }
    }
}

extern "C" void kernel_launch(void* const* d_in, const int* in_sizes, int n_in,
                              void* d_out, int out_size, void* d_ws, size_t ws_size,
                              hipStream_t stream) {
    const float* p = (const float*)d_in[0];
    int N = in_sizes[0] / 3;           // 524288
    int B = in_sizes[1];               // 8
    int n = N / B;                     // 65536
    int m = (out_size / B - 1) / 4;    // 1024

    float* out_np  = (float*)d_out;
    float* out_no  = out_np + (size_t)B * m * 3;
    float* out_idx = out_no + B;

    u64* comm = (u64*)d_ws;
    // clear all slot cells every launch (graph-safe, replay-deterministic)
    hipMemsetAsync(d_ws, 0, (size_t)B * 2 * NSLOT * sizeof(u64), stream);

    fps_slots<<<B * G, BS, 0, stream>>>(p, n, m, comm, out_np, out_no, out_idx);
}

// Round 8
// 2530.780 us; speedup vs baseline: 2.0510x; 2.0510x over previous
//
#include <hip/hip_runtime.h>
#include <stdint.h>

// Farthest point sampling, pointops semantics.
// B=8 batches, n=65536, stride=64 -> m=1024 samples/batch.
// 16 WGs/batch. Coords in LDS as float4 chunks (ds_read_b128). Per-step
// sync: each WG's t0 publishes ONE self-contained packed key
// (it|dist|~idx) to its own slot with a relaxed agent (sc1) store; wave 0
// lanes 0..15 poll the 16 slots (2 cachelines) until all carry tag==it,
// shfl-max the keys, broadcast via LDS. No atomicMax, no arrival counter,
// no acquire (no buffer_inv), 2 __syncthreads per step.
//
// Safety (monotone-tag parity induction, as round 7): slot s's parity cell
// for step it is overwritten only by publish(it+2) from WG s, which happens
// after WG s passed poll(it+1), which requires EVERY WG to have published
// it+1, which each does only after completing its poll(it). So no poller of
// step it can observe an it+2 value, and no deadlock. Keys are
// single-copy-atomic 8B; they carry all decision data, so no data/flag
// ordering is needed anywhere. comm is memset every launch.

#define G     16     // workgroups per batch
#define BS    256    // threads per workgroup (4 waves)
#define PPT   16     // points per thread (G*BS*PPT == n)
#define NC    (PPT/4)

typedef unsigned long long u64;
typedef unsigned int u32;

// key layout: [63:48]=it  [47:16]=float bits of best dist (nonneg)
//             [15:0]=0xFFFF-idx  (bigger wins => smaller idx wins ties,
//             numpy argmax first-max semantics; nonneg IEEE floats compare
//             like their bit patterns)

__global__ __launch_bounds__(BS, 1)
void fps_slots(const float* __restrict__ p, int n, int m,
               u64* __restrict__ comm,
               float* __restrict__ out_np, float* __restrict__ out_no,
               float* __restrict__ out_idx)
{
#pragma clang fp contract(off)
    const int bg   = blockIdx.x;
    const int b    = bg / G;
    const int g    = bg % G;
    const int t    = threadIdx.x;
    const int lane = t & 63;
    const int w    = t >> 6;
    const int gbase  = b * n;            // global point base of this batch
    const int wgbase = g * (BS * PPT);   // batch-local base of this WG

    // chunk c of thread t = points wgbase + t*PPT + c*4 .. +3
    __shared__ float4 xs[NC * BS], ys[NC * BS], zs[NC * BS];   // 48 KB
    __shared__ float s_val[BS / 64];
    __shared__ int   s_idx[BS / 64];
    __shared__ int   s_k;

    // ---- stage coords into LDS (one-time; 12 float4 global loads) ----
    {
        const float4* pb = (const float4*)(p + 3ull * (u32)(gbase + wgbase + t * PPT));
        float c[12 * 4];
#pragma unroll
        for (int v = 0; v < 12; ++v) {
            float4 f = pb[v];
            c[4 * v + 0] = f.x; c[4 * v + 1] = f.y; c[4 * v + 2] = f.z; c[4 * v + 3] = f.w;
        }
#pragma unroll
        for (int cc = 0; cc < NC; ++cc) {
            float4 X, Y, Z;
            X.x = c[(cc * 4 + 0) * 3 + 0]; X.y = c[(cc * 4 + 1) * 3 + 0];
            X.z = c[(cc * 4 + 2) * 3 + 0]; X.w = c[(cc * 4 + 3) * 3 + 0];
            Y.x = c[(cc * 4 + 0) * 3 + 1]; Y.y = c[(cc * 4 + 1) * 3 + 1];
            Y.z = c[(cc * 4 + 2) * 3 + 1]; Y.w = c[(cc * 4 + 3) * 3 + 1];
            Z.x = c[(cc * 4 + 0) * 3 + 2]; Z.y = c[(cc * 4 + 1) * 3 + 2];
            Z.z = c[(cc * 4 + 2) * 3 + 2]; Z.w = c[(cc * 4 + 3) * 3 + 2];
            xs[cc * BS + t] = X; ys[cc * BS + t] = Y; zs[cc * BS + t] = Z;
        }
    }
    __syncthreads();

    float dist[PPT];
#pragma unroll
    for (int j = 0; j < PPT; ++j) dist[j] = 1e10f;

    // first query = point 0 of the batch
    float qx = p[3ull * (u32)gbase + 0];
    float qy = p[3ull * (u32)gbase + 1];
    float qz = p[3ull * (u32)gbase + 2];

    if (g == 0 && t == 0) {
        out_idx[(size_t)b * m] = (float)gbase;
        out_np[(size_t)(b * m) * 3 + 0] = qx;
        out_np[(size_t)(b * m) * 3 + 1] = qy;
        out_np[(size_t)(b * m) * 3 + 2] = qz;
        out_no[b] = (float)((b + 1) * m);
    }

    // per-batch comm: 2 parities x 16 slots x u64 (512B stride per batch)
    u64* sb0 = comm + (size_t)b * 64;

    for (int it = 1; it < m; ++it) {
        // stop LDS values from being promoted/cached across steps
        asm volatile("" ::: "memory");

        // ---- local distance update + per-thread argmax (ids ascend in j) ----
        float best = -1.0f;
        int   bj   = 0;
#pragma unroll
        for (int cc = 0; cc < NC; ++cc) {
            float4 X = xs[cc * BS + t];
            float4 Y = ys[cc * BS + t];
            float4 Z = zs[cc * BS + t];
            float xl[4] = {X.x, X.y, X.z, X.w};
            float yl[4] = {Y.x, Y.y, Y.z, Y.w};
            float zl[4] = {Z.x, Z.y, Z.z, Z.w};
#pragma unroll
            for (int e = 0; e < 4; ++e) {
                float dx = xl[e] - qx;
                float dy = yl[e] - qy;
                float dz = zl[e] - qz;
                float d  = dx * dx + dy * dy + dz * dz;  // contract off: left-assoc
                int j = cc * 4 + e;
                float nd = fminf(dist[j], d);
                dist[j] = nd;
                if (nd > best) { best = nd; bj = j; }    // strict > keeps earliest
            }
        }
        int bidx = wgbase + t * PPT + bj;                // batch-local winner idx

        // ---- wave argmax (64 lanes; ids ascend with lane) ----
#pragma unroll
        for (int off = 1; off < 64; off <<= 1) {
            float ov = __shfl_xor(best, off);
            int   oi = __shfl_xor(bidx, off);
            if (ov > best || (ov == best && oi < bidx)) { best = ov; bidx = oi; }
        }
        if (lane == 0) { s_val[w] = best; s_idx[w] = bidx; }
        __syncthreads();

        u64* sb = sb0 + (size_t)(it & 1) * 16;

        if (w == 0) {
            // ---- lane 0: WG reduce + publish self-contained key ----
            if (lane == 0) {
                float v = -1.0f; int ix = 0x7fffffff;
#pragma unroll
                for (int ww = 0; ww < BS / 64; ++ww) {
                    if (s_val[ww] > v || (s_val[ww] == v && s_idx[ww] < ix)) {
                        v = s_val[ww]; ix = s_idx[ww];
                    }
                }
                u64 k = ((u64)(u32)it << 48)
                      | ((u64)(u32)__float_as_uint(v) << 16)
                      | (u64)(u32)(0xFFFF - ix);
                __hip_atomic_store(sb + g, k, __ATOMIC_RELAXED,
                                   __HIP_MEMORY_SCOPE_AGENT);
            }
            // ---- lanes 0..15: poll the 16 slots until all tagged it ----
            u64 k = 0;
            bool ok;
            do {
                if (lane < G) {
                    k = __hip_atomic_load(sb + lane, __ATOMIC_RELAXED,
                                          __HIP_MEMORY_SCOPE_AGENT);
                    ok = ((u32)(k >> 48) == (u32)it);
                } else ok = true;
            } while (!__all(ok));
            // ---- max over 16 keys (xor stages stay within 16-lane group) ----
#pragma unroll
            for (int off = 1; off < G; off <<= 1) {
                u64 k2 = __shfl_xor(k, off);
                if (k2 > k) k = k2;
            }
            if (lane == 0) s_k = 0xFFFF - (int)(k & 0xFFFF);
        }
        __syncthreads();
        int kidx = s_k;

        // winner coords from read-only p (L1/L2-warm: loop has no cache-inv)
        const float* wp = p + 3ull * (u32)(gbase + kidx);
        qx = wp[0]; qy = wp[1]; qz = wp[2];

        if (g == 0 && t == 0) {
            out_idx[(size_t)b * m + it] = (float)(gbase + kidx);
            out_np[(size_t)(b * m + it) * 3 + 0] = qx;
            out_np[(size_t)(b * m + it) * 3 + 1] = qy;
            out_np[(size_t)(b * m + it) * 3 + 2] = qz;
        }
    }
}

extern "C" void kernel_launch(void* const* d_in, const int* in_sizes, int n_in,
                              void* d_out, int out_size, void* d_ws, size_t ws_size,
                              hipStream_t stream) {
    const float* p = (const float*)d_in[0];
    int N = in_sizes[0] / 3;           // 524288
    int B = in_sizes[1];               // 8
    int n = N / B;                     // 65536
    int m = (out_size / B - 1) / 4;    // 1024

    float* out_np  = (float*)d_out;
    float* out_no  = out_np + (size_t)B * m * 3;
    float* out_idx = out_no + B;

    u64* comm = (u64*)d_ws;
    // clear all slot cells every launch (graph-safe, replay-deterministic)
    hipMemsetAsync(d_ws, 0, (size_t)B * 64 * sizeof(u64), stream);

    fps_slots<<<B * G, BS, 0, stream>>>(p, n, m, comm, out_np, out_no, out_idx);
}